// Round 11
// baseline (375.700 us; speedup 1.0000x reference)
//
#include <hip/hip_runtime.h>

#define N_NODES 100000
#define N_EDGES 1600000
#define NB_SCAN 391    // ceil(N_NODES / 256)
#define NSLICE 64      // edge slices
#define SLICE_E 25000  // N_EDGES / NSLICE
#define NBUCK 4        // node buckets
#define BUCK_N 25000   // nodes per bucket (N_NODES / NBUCK)
#define BUCK_W 12500   // uint32 words per bucket (2x uint16 packed)

__device__ __forceinline__ unsigned short f2bf(float f) {   // RNE fp32->bf16
    unsigned int u = __float_as_uint(f);
    return (unsigned short)((u + 0x7FFFu + ((u >> 16) & 1u)) >> 16);
}
__device__ __forceinline__ float bf2f(unsigned short b) {
    return __uint_as_float(((unsigned int)b) << 16);
}

// ---------------- LDS-bucketed histogram (no global atomics) ----------------

template <bool RANK>
__global__ void __launch_bounds__(512) count_kernel(
        const int* __restrict__ ids,
        unsigned short* __restrict__ slicecnt,   // [NSLICE][N_NODES] u16
        unsigned short* __restrict__ rank16) {   // [N_EDGES] u16 (RANK only)
    __shared__ unsigned int cnt[BUCK_W];
    int s = blockIdx.x >> 2;
    int b = blockIdx.x & 3;
    int b0 = b * BUCK_N;
    for (int w = threadIdx.x; w < BUCK_W; w += 512) cnt[w] = 0;
    __syncthreads();
    int base = s * SLICE_E;
    for (int i = threadIdx.x; i < SLICE_E; i += 512) {
        int e = base + i;
        int id = ids[e] - b0;
        if ((unsigned)id < (unsigned)BUCK_N) {
            unsigned int shift = (id & 1) * 16;
            unsigned int old = atomicAdd(&cnt[id >> 1], 1u << shift);
            if (RANK) rank16[e] = (unsigned short)((old >> shift) & 0xFFFFu);
        }
    }
    __syncthreads();
    unsigned int* row = (unsigned int*)(slicecnt + (size_t)s * N_NODES) + b * BUCK_W;
    for (int w = threadIdx.x; w < BUCK_W; w += 512) row[w] = cnt[w];
}

// per-node scan over slice counts: dst counts -> slice offsets (in place),
// in-degree + both norms (rsqrt fused). src counts only summed.
__global__ void scan_slices_kernel(unsigned short* __restrict__ scd,
                                   const unsigned short* __restrict__ scs,
                                   int* __restrict__ deg_int,
                                   float* __restrict__ norm_dst,
                                   float* __restrict__ norm_src) {
    int n = blockIdx.x * blockDim.x + threadIdx.x;
    if (n >= N_NODES) return;
    unsigned int tot = 0;
    for (int s = 0; s < NSLICE; ++s) {
        size_t idx = (size_t)s * N_NODES + n;
        unsigned int c = scd[idx];
        scd[idx] = (unsigned short)tot;
        tot += c;
    }
    deg_int[n] = (int)tot;
    norm_dst[n] = rsqrtf(fmaxf((float)tot, 1.0f));
    unsigned int so = 0;
    for (int s = 0; s < NSLICE; ++s) so += scs[(size_t)s * N_NODES + n];
    norm_src[n] = rsqrtf(fmaxf((float)so, 1.0f));
}

// ---------------- 3-phase device-wide exclusive scan of in-degrees ----------------

__global__ void block_sum_kernel(const int* __restrict__ deg_in, int* __restrict__ block_sums) {
    __shared__ int sdata[256];
    int t = threadIdx.x;
    int n = blockIdx.x * 256 + t;
    int v = (n < N_NODES) ? deg_in[n] : 0;
    sdata[t] = v;
    __syncthreads();
    for (int off = 128; off > 0; off >>= 1) {
        if (t < off) sdata[t] += sdata[t + off];
        __syncthreads();
    }
    if (t == 0) block_sums[blockIdx.x] = sdata[0];
}

__global__ void scan_blocks_kernel(const int* __restrict__ block_sums, int* __restrict__ block_off) {
    __shared__ int part[512];
    int t = threadIdx.x;
    int v = (t < NB_SCAN) ? block_sums[t] : 0;
    part[t] = v;
    __syncthreads();
    for (int off = 1; off < 512; off <<= 1) {
        int u = (t >= off) ? part[t - off] : 0;
        __syncthreads();
        part[t] += u;
        __syncthreads();
    }
    if (t < NB_SCAN) block_off[t] = part[t] - v;   // exclusive
}

__global__ void scatter_rowptr_kernel(const int* __restrict__ deg_in,
                                      const int* __restrict__ block_off,
                                      int* __restrict__ row_ptr) {
    __shared__ int part[256];
    int t = threadIdx.x;
    int n = blockIdx.x * 256 + t;
    int v = (n < N_NODES) ? deg_in[n] : 0;
    part[t] = v;
    __syncthreads();
    for (int off = 1; off < 256; off <<= 1) {
        int u = (t >= off) ? part[t - off] : 0;
        __syncthreads();
        part[t] += u;
        __syncthreads();
    }
    int excl = part[t] - v + block_off[blockIdx.x];
    if (n < N_NODES) row_ptr[n] = excl;
    if (n == N_NODES - 1) row_ptr[N_NODES] = excl + v;
}

// ---------------- atomic-free CSR fill ----------------
// slot = row_ptr[d] + sliceoff[slice][d] + rank-within-slice  (a permutation)

__global__ void fill_kernel(const int* __restrict__ src, const int* __restrict__ dst,
                            const float* __restrict__ ew,
                            const float* __restrict__ ns, const float* __restrict__ nd,
                            const int* __restrict__ row_ptr,
                            const unsigned short* __restrict__ sliceoff,
                            const unsigned short* __restrict__ rank16,
                            int2* __restrict__ epack) {
    int i = blockIdx.x * blockDim.x + threadIdx.x;
    int stride = gridDim.x * blockDim.x;
    for (int e = i; e < N_EDGES; e += stride) {
        int s = src[e], d = dst[e];
        int sl = e / SLICE_E;
        int slot = row_ptr[d] + (int)sliceoff[(size_t)sl * N_NODES + d] + (int)rank16[e];
        float c = ns[s] * ew[e] * nd[d];
        epack[slot] = make_int2(s, __float_as_int(c));
    }
}

// ---------------- standalone dense transform: h = x @ W  -> bf16 ----------------

template <int BM, int DOUT>
__global__ void __launch_bounds__(256) matmul_kernel(
        const float* __restrict__ x, const float* __restrict__ W,
        unsigned short* __restrict__ h) {
    constexpr int S = 65;
    constexpr int CG = DOUT / 4;
    __shared__ float Xs[BM * S];
    __shared__ float Ws[64 * DOUT];
    int tid = threadIdx.x;
    int n0 = blockIdx.x * BM;

    for (int i = tid; i < 16 * DOUT; i += 256)
        ((float4*)Ws)[i] = ((const float4*)W)[i];

    int c0 = (tid & 15) * 4;
    for (int r = tid >> 4; r < BM; r += 16) {
        int n = n0 + r;
        int nc = n < N_NODES ? n : N_NODES - 1;
        float4 v = ((const float4*)(x + (size_t)nc * 64))[tid & 15];
        Xs[r * S + c0]     = v.x;
        Xs[r * S + c0 + 1] = v.y;
        Xs[r * S + c0 + 2] = v.z;
        Xs[r * S + c0 + 3] = v.w;
    }
    __syncthreads();

    int cg = tid % CG;
    int ng = tid / CG;
    float acc[4][4];
#pragma unroll
    for (int i = 0; i < 4; ++i)
#pragma unroll
        for (int j = 0; j < 4; ++j) acc[i][j] = 0.0f;

#pragma unroll 16
    for (int k = 0; k < 64; ++k) {
        float4 wk = *(const float4*)(&Ws[k * DOUT + cg * 4]);
        float xk[4];
#pragma unroll
        for (int i = 0; i < 4; ++i) xk[i] = Xs[(ng * 4 + i) * S + k];
#pragma unroll
        for (int i = 0; i < 4; ++i) {
            acc[i][0] = fmaf(xk[i], wk.x, acc[i][0]);
            acc[i][1] = fmaf(xk[i], wk.y, acc[i][1]);
            acc[i][2] = fmaf(xk[i], wk.z, acc[i][2]);
            acc[i][3] = fmaf(xk[i], wk.w, acc[i][3]);
        }
    }

#pragma unroll
    for (int i = 0; i < 4; ++i) {
        int n = n0 + ng * 4 + i;
        if (n < N_NODES) {
            ushort4 o;
            o.x = f2bf(acc[i][0]); o.y = f2bf(acc[i][1]);
            o.z = f2bf(acc[i][2]); o.w = f2bf(acc[i][3]);
            *(ushort4*)(&h[(size_t)n * DOUT + cg * 4]) = o;
        }
    }
}

// ---------------- fused: agg(hin) -> +bias -> relu -> @W -> bf16 hout ----------------
// 512 threads = 8 waves; each wave gathers 16 nodes (D=64 lanes) straight into
// the LDS X-tile (removes the fp32 agg round-trip through HBM/L2), then the
// block runs the register-tiled matmul. hin/hout MUST be distinct buffers.

template <int DOUT>
__global__ void __launch_bounds__(512) agg_mm_kernel(
        const int* __restrict__ row_ptr,
        const int2* __restrict__ epack,
        const unsigned short* __restrict__ hin,
        const float* __restrict__ bias_in,   // bias of aggregated layer (pre-relu)
        const float* __restrict__ W,         // [64][DOUT]
        unsigned short* __restrict__ hout) {
    constexpr int BM = 128;
    constexpr int S = 65;
    constexpr int CG = DOUT / 4;             // 16 (d64) or 8 (d32)
    constexpr int RI = BM * CG / 512;        // rows/thread: 4 (d64) or 2 (d32)
    __shared__ float Xs[BM * S];
    __shared__ float Ws[64 * DOUT];
    int tid = threadIdx.x;
    int n0 = blockIdx.x * BM;

    for (int i = tid; i < 16 * DOUT; i += 512)
        ((float4*)Ws)[i] = ((const float4*)W)[i];

    int lane = tid & 63;
    int wid = tid >> 6;                       // 0..7
    float bv = bias_in[lane];
    const unsigned short* hl = hin + lane;

    for (int j = 0; j < 16; ++j) {
        int n = n0 + wid * 16 + j;
        float a0 = 0.f, a1 = 0.f, a2 = 0.f, a3 = 0.f;
        float a4 = 0.f, a5 = 0.f, a6 = 0.f, a7 = 0.f;
        if (n < N_NODES) {
            int s = row_ptr[n];
            int e = row_ptr[n + 1];
            int i = s;
            for (; i + 7 < e; i += 8) {
                int2 p0 = epack[i],     p1 = epack[i + 1], p2 = epack[i + 2], p3 = epack[i + 3];
                int2 p4 = epack[i + 4], p5 = epack[i + 5], p6 = epack[i + 6], p7 = epack[i + 7];
                float h0 = bf2f(hl[(size_t)p0.x * 64]);
                float h1 = bf2f(hl[(size_t)p1.x * 64]);
                float h2 = bf2f(hl[(size_t)p2.x * 64]);
                float h3 = bf2f(hl[(size_t)p3.x * 64]);
                float h4 = bf2f(hl[(size_t)p4.x * 64]);
                float h5 = bf2f(hl[(size_t)p5.x * 64]);
                float h6 = bf2f(hl[(size_t)p6.x * 64]);
                float h7 = bf2f(hl[(size_t)p7.x * 64]);
                a0 = fmaf(h0, __int_as_float(p0.y), a0);
                a1 = fmaf(h1, __int_as_float(p1.y), a1);
                a2 = fmaf(h2, __int_as_float(p2.y), a2);
                a3 = fmaf(h3, __int_as_float(p3.y), a3);
                a4 = fmaf(h4, __int_as_float(p4.y), a4);
                a5 = fmaf(h5, __int_as_float(p5.y), a5);
                a6 = fmaf(h6, __int_as_float(p6.y), a6);
                a7 = fmaf(h7, __int_as_float(p7.y), a7);
            }
            for (; i + 3 < e; i += 4) {
                int2 p0 = epack[i], p1 = epack[i + 1], p2 = epack[i + 2], p3 = epack[i + 3];
                a0 = fmaf(bf2f(hl[(size_t)p0.x * 64]), __int_as_float(p0.y), a0);
                a1 = fmaf(bf2f(hl[(size_t)p1.x * 64]), __int_as_float(p1.y), a1);
                a2 = fmaf(bf2f(hl[(size_t)p2.x * 64]), __int_as_float(p2.y), a2);
                a3 = fmaf(bf2f(hl[(size_t)p3.x * 64]), __int_as_float(p3.y), a3);
            }
            for (; i < e; ++i) {
                int2 p = epack[i];
                a0 = fmaf(bf2f(hl[(size_t)p.x * 64]), __int_as_float(p.y), a0);
            }
        }
        float acc = ((a0 + a1) + (a2 + a3)) + ((a4 + a5) + (a6 + a7));
        Xs[(wid * 16 + j) * S + lane] = fmaxf(acc + bv, 0.0f);
    }
    __syncthreads();

    int cg = tid % CG;
    int ng = tid / CG;
    float acc[RI][4];
#pragma unroll
    for (int i = 0; i < RI; ++i)
#pragma unroll
        for (int j = 0; j < 4; ++j) acc[i][j] = 0.0f;

#pragma unroll 16
    for (int k = 0; k < 64; ++k) {
        float4 wk = *(const float4*)(&Ws[k * DOUT + cg * 4]);
        float xk[RI];
#pragma unroll
        for (int i = 0; i < RI; ++i) xk[i] = Xs[(ng * RI + i) * S + k];
#pragma unroll
        for (int i = 0; i < RI; ++i) {
            acc[i][0] = fmaf(xk[i], wk.x, acc[i][0]);
            acc[i][1] = fmaf(xk[i], wk.y, acc[i][1]);
            acc[i][2] = fmaf(xk[i], wk.z, acc[i][2]);
            acc[i][3] = fmaf(xk[i], wk.w, acc[i][3]);
        }
    }

#pragma unroll
    for (int i = 0; i < RI; ++i) {
        int n = n0 + ng * RI + i;
        if (n < N_NODES) {
            ushort4 o;
            o.x = f2bf(acc[i][0]); o.y = f2bf(acc[i][1]);
            o.z = f2bf(acc[i][2]); o.w = f2bf(acc[i][3]);
            *(ushort4*)(&hout[(size_t)n * DOUT + cg * 4]) = o;
        }
    }
}

// ---------------- final CSR aggregation (bf16 gather, +bias, fp32 out) ----------------

template <int D>
__global__ void __launch_bounds__(256) csr_agg_kernel(
        const int* __restrict__ row_ptr,
        const int2* __restrict__ epack,
        const unsigned short* __restrict__ h,
        const float* __restrict__ bias, float* __restrict__ out) {
    int tid = blockIdx.x * blockDim.x + threadIdx.x;
    int stride = gridDim.x * blockDim.x;
    int lane = threadIdx.x & (D - 1);
    int node0 = tid / D;
    int nstride = stride / D;
    const unsigned short* hl = h + lane;
    for (int n = node0; n < N_NODES; n += nstride) {
        int s = row_ptr[n];
        int e = row_ptr[n + 1];
        float a0 = 0.f, a1 = 0.f, a2 = 0.f, a3 = 0.f;
        float a4 = 0.f, a5 = 0.f, a6 = 0.f, a7 = 0.f;
        int i = s;
        for (; i + 7 < e; i += 8) {
            int2 p0 = epack[i],     p1 = epack[i + 1], p2 = epack[i + 2], p3 = epack[i + 3];
            int2 p4 = epack[i + 4], p5 = epack[i + 5], p6 = epack[i + 6], p7 = epack[i + 7];
            a0 = fmaf(bf2f(hl[(size_t)p0.x * D]), __int_as_float(p0.y), a0);
            a1 = fmaf(bf2f(hl[(size_t)p1.x * D]), __int_as_float(p1.y), a1);
            a2 = fmaf(bf2f(hl[(size_t)p2.x * D]), __int_as_float(p2.y), a2);
            a3 = fmaf(bf2f(hl[(size_t)p3.x * D]), __int_as_float(p3.y), a3);
            a4 = fmaf(bf2f(hl[(size_t)p4.x * D]), __int_as_float(p4.y), a4);
            a5 = fmaf(bf2f(hl[(size_t)p5.x * D]), __int_as_float(p5.y), a5);
            a6 = fmaf(bf2f(hl[(size_t)p6.x * D]), __int_as_float(p6.y), a6);
            a7 = fmaf(bf2f(hl[(size_t)p7.x * D]), __int_as_float(p7.y), a7);
        }
        for (; i + 3 < e; i += 4) {
            int2 p0 = epack[i], p1 = epack[i + 1], p2 = epack[i + 2], p3 = epack[i + 3];
            a0 = fmaf(bf2f(hl[(size_t)p0.x * D]), __int_as_float(p0.y), a0);
            a1 = fmaf(bf2f(hl[(size_t)p1.x * D]), __int_as_float(p1.y), a1);
            a2 = fmaf(bf2f(hl[(size_t)p2.x * D]), __int_as_float(p2.y), a2);
            a3 = fmaf(bf2f(hl[(size_t)p3.x * D]), __int_as_float(p3.y), a3);
        }
        for (; i < e; ++i) {
            int2 p = epack[i];
            a0 = fmaf(bf2f(hl[(size_t)p.x * D]), __int_as_float(p.y), a0);
        }
        float acc = ((a0 + a1) + (a2 + a3)) + ((a4 + a5) + (a6 + a7));
        out[(size_t)n * D + lane] = acc + bias[lane];
    }
}

extern "C" void kernel_launch(void* const* d_in, const int* in_sizes, int n_in,
                              void* d_out, int out_size, void* d_ws, size_t ws_size,
                              hipStream_t stream) {
    const float* features = (const float*)d_in[0];
    const float* ew       = (const float*)d_in[1];
    const int*   src      = (const int*)d_in[2];
    const int*   dst      = (const int*)d_in[3];
    const float* W1       = (const float*)d_in[4];
    const float* b1       = (const float*)d_in[5];
    const float* W2       = (const float*)d_in[6];
    const float* b2       = (const float*)d_in[7];
    const float* Wp       = (const float*)d_in[8];
    const float* bp       = (const float*)d_in[9];
    float* out = (float*)d_out;

    // workspace layout (explicit 4B-unit offsets)
    float* ws = (float*)d_ws;
    float* norm_src = ws;                             // @0        N
    float* norm_dst = ws + 100000;                    // @100000   N
    int*   deg_int  = (int*)(ws + 200000);            // @200000   N
    int*   row_ptr  = (int*)(ws + 300000);            // @300000   N+1
    int*   block_sums = (int*)(ws + 400002);          // @400002   NB_SCAN
    int*   block_off  = (int*)(ws + 400394);          // @400394   NB_SCAN
    unsigned short* rank16 = (unsigned short*)(ws + 400800); // 1.6M u16
    int2*  epack = (int2*)(ws + 1200800);             // E int2 (byte off %8 == 0)
    unsigned short* hbufA = (unsigned short*)(ws + 4400800);  // N*64 bf16
    unsigned short* hbufB = (unsigned short*)(ws + 10800800); // N*64 bf16

    // slice-count buffers alias hbufA/hbufB (dead once fill completes)
    unsigned short* slicecnt_dst = hbufA;   // becomes sliceoff in-place
    unsigned short* slicecnt_src = hbufB;

    // ---- CSR + norms build: zero global atomics ----
    count_kernel<true><<<NSLICE * NBUCK, 512, 0, stream>>>(dst, slicecnt_dst, rank16);
    count_kernel<false><<<NSLICE * NBUCK, 512, 0, stream>>>(src, slicecnt_src, nullptr);
    scan_slices_kernel<<<NB_SCAN, 256, 0, stream>>>(slicecnt_dst, slicecnt_src,
                                                    deg_int, norm_dst, norm_src);
    block_sum_kernel<<<NB_SCAN, 256, 0, stream>>>(deg_int, block_sums);
    scan_blocks_kernel<<<1, 512, 0, stream>>>(block_sums, block_off);
    scatter_rowptr_kernel<<<NB_SCAN, 256, 0, stream>>>(deg_int, block_off, row_ptr);
    fill_kernel<<<2048, 256, 0, stream>>>(src, dst, ew, norm_src, norm_dst,
                                          row_ptr, slicecnt_dst, rank16, epack);

    // ---- layer 1 matmul: h1 = features @ W1  (bias deferred into fused layer 2)
    matmul_kernel<64, 64><<<1563, 256, 0, stream>>>(features, W1, hbufA);

    // ---- fused layer 2: h2 = relu(A*h1 + b1) @ W2
    agg_mm_kernel<64><<<782, 512, 0, stream>>>(row_ptr, epack, hbufA, b1, W2, hbufB);

    // ---- fused layer 3 matmul: h3 = relu(A*h2 + b2) @ Wp
    agg_mm_kernel<32><<<782, 512, 0, stream>>>(row_ptr, epack, hbufB, b2, Wp, hbufA);

    // ---- final aggregation: out = A*h3 + bp
    csr_agg_kernel<32><<<4096, 256, 0, stream>>>(row_ptr, epack, hbufA, bp, out);
}

// Round 12
// 289.709 us; speedup vs baseline: 1.2968x; 1.2968x over previous
//
#include <hip/hip_runtime.h>

#define N_NODES 100000
#define N_EDGES 1600000
#define NB_SCAN 391    // ceil(N_NODES / 256)
#define NSLICE 64      // edge slices
#define SLICE_E 25000  // N_EDGES / NSLICE
#define NBUCK 4        // node buckets
#define BUCK_N 25000   // nodes per bucket (N_NODES / NBUCK)
#define BUCK_W 12500   // uint32 words per bucket (2x uint16 packed)

__device__ __forceinline__ unsigned short f2bf(float f) {   // RNE fp32->bf16
    unsigned int u = __float_as_uint(f);
    return (unsigned short)((u + 0x7FFFu + ((u >> 16) & 1u)) >> 16);
}
__device__ __forceinline__ float bf2f(unsigned short b) {
    return __uint_as_float(((unsigned int)b) << 16);
}

// ---------------- LDS-bucketed histogram (no global atomics) ----------------

template <bool RANK>
__global__ void __launch_bounds__(512) count_kernel(
        const int* __restrict__ ids,
        unsigned short* __restrict__ slicecnt,   // [NSLICE][N_NODES] u16
        unsigned short* __restrict__ rank16) {   // [N_EDGES] u16 (RANK only)
    __shared__ unsigned int cnt[BUCK_W];
    int s = blockIdx.x >> 2;
    int b = blockIdx.x & 3;
    int b0 = b * BUCK_N;
    for (int w = threadIdx.x; w < BUCK_W; w += 512) cnt[w] = 0;
    __syncthreads();
    int base = s * SLICE_E;
    for (int i = threadIdx.x; i < SLICE_E; i += 512) {
        int e = base + i;
        int id = ids[e] - b0;
        if ((unsigned)id < (unsigned)BUCK_N) {
            unsigned int shift = (id & 1) * 16;
            unsigned int old = atomicAdd(&cnt[id >> 1], 1u << shift);
            if (RANK) rank16[e] = (unsigned short)((old >> shift) & 0xFFFFu);
        }
    }
    __syncthreads();
    unsigned int* row = (unsigned int*)(slicecnt + (size_t)s * N_NODES) + b * BUCK_W;
    for (int w = threadIdx.x; w < BUCK_W; w += 512) row[w] = cnt[w];
}

// per-node scan over slice counts: dst counts -> slice offsets (in place),
// in-degree + norms. norm_dst pre-scaled by 1/32767 (ew 15-bit dequant folded).
__global__ void scan_slices_kernel(unsigned short* __restrict__ scd,
                                   const unsigned short* __restrict__ scs,
                                   int* __restrict__ deg_int,
                                   float* __restrict__ ndq,
                                   float* __restrict__ norm_src) {
    int n = blockIdx.x * blockDim.x + threadIdx.x;
    if (n >= N_NODES) return;
    unsigned int tot = 0;
    for (int s = 0; s < NSLICE; ++s) {
        size_t idx = (size_t)s * N_NODES + n;
        unsigned int c = scd[idx];
        scd[idx] = (unsigned short)tot;
        tot += c;
    }
    deg_int[n] = (int)tot;
    ndq[n] = rsqrtf(fmaxf((float)tot, 1.0f)) * (1.0f / 32767.0f);
    unsigned int so = 0;
    for (int s = 0; s < NSLICE; ++s) so += scs[(size_t)s * N_NODES + n];
    norm_src[n] = rsqrtf(fmaxf((float)so, 1.0f));
}

// ---------------- 3-phase device-wide exclusive scan of in-degrees ----------------

__global__ void block_sum_kernel(const int* __restrict__ deg_in, int* __restrict__ block_sums) {
    __shared__ int sdata[256];
    int t = threadIdx.x;
    int n = blockIdx.x * 256 + t;
    int v = (n < N_NODES) ? deg_in[n] : 0;
    sdata[t] = v;
    __syncthreads();
    for (int off = 128; off > 0; off >>= 1) {
        if (t < off) sdata[t] += sdata[t + off];
        __syncthreads();
    }
    if (t == 0) block_sums[blockIdx.x] = sdata[0];
}

__global__ void scan_blocks_kernel(const int* __restrict__ block_sums, int* __restrict__ block_off) {
    __shared__ int part[512];
    int t = threadIdx.x;
    int v = (t < NB_SCAN) ? block_sums[t] : 0;
    part[t] = v;
    __syncthreads();
    for (int off = 1; off < 512; off <<= 1) {
        int u = (t >= off) ? part[t - off] : 0;
        __syncthreads();
        part[t] += u;
        __syncthreads();
    }
    if (t < NB_SCAN) block_off[t] = part[t] - v;   // exclusive
}

__global__ void scatter_rowptr_kernel(const int* __restrict__ deg_in,
                                      const int* __restrict__ block_off,
                                      int* __restrict__ row_ptr) {
    __shared__ int part[256];
    int t = threadIdx.x;
    int n = blockIdx.x * 256 + t;
    int v = (n < N_NODES) ? deg_in[n] : 0;
    part[t] = v;
    __syncthreads();
    for (int off = 1; off < 256; off <<= 1) {
        int u = (t >= off) ? part[t - off] : 0;
        __syncthreads();
        part[t] += u;
        __syncthreads();
    }
    int excl = part[t] - v + block_off[blockIdx.x];
    if (n < N_NODES) row_ptr[n] = excl;
    if (n == N_NODES - 1) row_ptr[N_NODES] = excl + v;
}

// ---------------- atomic-free CSR fill (4B packed records) ----------------
// slot = row_ptr[d] + sliceoff[slice][d] + rank  ;  rec = (src<<15) | ew15
// ns/nd NOT read here: ns folded into h rows (matmul), nd into agg epilogue.

__global__ void fill_kernel(const int* __restrict__ src, const int* __restrict__ dst,
                            const float* __restrict__ ew,
                            const int* __restrict__ row_ptr,
                            const unsigned short* __restrict__ sliceoff,
                            const unsigned short* __restrict__ rank16,
                            unsigned int* __restrict__ epack) {
    int i = blockIdx.x * blockDim.x + threadIdx.x;
    int stride = gridDim.x * blockDim.x;
    for (int e = i; e < N_EDGES; e += stride) {
        int s = src[e], d = dst[e];
        int sl = e / SLICE_E;
        int slot = row_ptr[d] + (int)sliceoff[(size_t)sl * N_NODES + d] + (int)rank16[e];
        unsigned int q = (unsigned int)(ew[e] * 32767.0f + 0.5f);
        epack[slot] = ((unsigned int)s << 15) | q;
    }
}

// ---------------- dense transform: h = ns ⊙ (act(x [+b]) @ W) -> bf16 ----------------

template <int BM, int DOUT, bool BIAS_RELU>
__global__ void __launch_bounds__(256) matmul_kernel(
        const float* __restrict__ x, const float* __restrict__ W,
        const float* __restrict__ bin, const float* __restrict__ ns,
        unsigned short* __restrict__ h) {
    constexpr int S = 65;
    constexpr int CG = DOUT / 4;
    __shared__ float Xs[BM * S];
    __shared__ float Ws[64 * DOUT];
    int tid = threadIdx.x;
    int n0 = blockIdx.x * BM;

    for (int i = tid; i < 16 * DOUT; i += 256)
        ((float4*)Ws)[i] = ((const float4*)W)[i];

    float4 bv4;
    if (BIAS_RELU) bv4 = ((const float4*)bin)[tid & 15];
    int c0 = (tid & 15) * 4;
    for (int r = tid >> 4; r < BM; r += 16) {
        int n = n0 + r;
        int nc = n < N_NODES ? n : N_NODES - 1;
        float4 v = ((const float4*)(x + (size_t)nc * 64))[tid & 15];
        if (BIAS_RELU) {
            v.x = fmaxf(v.x + bv4.x, 0.0f);
            v.y = fmaxf(v.y + bv4.y, 0.0f);
            v.z = fmaxf(v.z + bv4.z, 0.0f);
            v.w = fmaxf(v.w + bv4.w, 0.0f);
        }
        Xs[r * S + c0]     = v.x;
        Xs[r * S + c0 + 1] = v.y;
        Xs[r * S + c0 + 2] = v.z;
        Xs[r * S + c0 + 3] = v.w;
    }
    __syncthreads();

    int cg = tid % CG;
    int ng = tid / CG;
    float acc[4][4];
#pragma unroll
    for (int i = 0; i < 4; ++i)
#pragma unroll
        for (int j = 0; j < 4; ++j) acc[i][j] = 0.0f;

#pragma unroll 16
    for (int k = 0; k < 64; ++k) {
        float4 wk = *(const float4*)(&Ws[k * DOUT + cg * 4]);
        float xk[4];
#pragma unroll
        for (int i = 0; i < 4; ++i) xk[i] = Xs[(ng * 4 + i) * S + k];
#pragma unroll
        for (int i = 0; i < 4; ++i) {
            acc[i][0] = fmaf(xk[i], wk.x, acc[i][0]);
            acc[i][1] = fmaf(xk[i], wk.y, acc[i][1]);
            acc[i][2] = fmaf(xk[i], wk.z, acc[i][2]);
            acc[i][3] = fmaf(xk[i], wk.w, acc[i][3]);
        }
    }

#pragma unroll
    for (int i = 0; i < 4; ++i) {
        int n = n0 + ng * 4 + i;
        if (n < N_NODES) {
            float nsv = ns[n];
            ushort4 o;
            o.x = f2bf(acc[i][0] * nsv); o.y = f2bf(acc[i][1] * nsv);
            o.z = f2bf(acc[i][2] * nsv); o.w = f2bf(acc[i][3] * nsv);
            *(ushort4*)(&h[(size_t)n * DOUT + cg * 4]) = o;
        }
    }
}

// ---------------- CSR aggregation (4B epack, bf16 h, fp32 accumulate) ----------------
// out[n] = ndq[n] * Σ ew15 * h[src]  (+bias if FINAL)

template <int D, bool FINAL>
__global__ void __launch_bounds__(256) csr_agg_kernel(
        const int* __restrict__ row_ptr,
        const unsigned int* __restrict__ epack,
        const unsigned short* __restrict__ h,
        const float* __restrict__ ndq,
        const float* __restrict__ bias, float* __restrict__ out) {
    int tid = blockIdx.x * blockDim.x + threadIdx.x;
    int stride = gridDim.x * blockDim.x;
    int lane = threadIdx.x & (D - 1);
    int node0 = tid / D;
    int nstride = stride / D;
    const unsigned short* hl = h + lane;
    for (int n = node0; n < N_NODES; n += nstride) {
        int s = row_ptr[n];
        int e = row_ptr[n + 1];
        float a0 = 0.f, a1 = 0.f, a2 = 0.f, a3 = 0.f;
        float a4 = 0.f, a5 = 0.f, a6 = 0.f, a7 = 0.f;
        int i = s;
        for (; i + 7 < e; i += 8) {
            unsigned int p0 = epack[i],     p1 = epack[i + 1], p2 = epack[i + 2], p3 = epack[i + 3];
            unsigned int p4 = epack[i + 4], p5 = epack[i + 5], p6 = epack[i + 6], p7 = epack[i + 7];
            float h0 = bf2f(hl[(size_t)(p0 >> 15) * D]);
            float h1 = bf2f(hl[(size_t)(p1 >> 15) * D]);
            float h2 = bf2f(hl[(size_t)(p2 >> 15) * D]);
            float h3 = bf2f(hl[(size_t)(p3 >> 15) * D]);
            float h4 = bf2f(hl[(size_t)(p4 >> 15) * D]);
            float h5 = bf2f(hl[(size_t)(p5 >> 15) * D]);
            float h6 = bf2f(hl[(size_t)(p6 >> 15) * D]);
            float h7 = bf2f(hl[(size_t)(p7 >> 15) * D]);
            a0 = fmaf((float)(p0 & 32767u), h0, a0);
            a1 = fmaf((float)(p1 & 32767u), h1, a1);
            a2 = fmaf((float)(p2 & 32767u), h2, a2);
            a3 = fmaf((float)(p3 & 32767u), h3, a3);
            a4 = fmaf((float)(p4 & 32767u), h4, a4);
            a5 = fmaf((float)(p5 & 32767u), h5, a5);
            a6 = fmaf((float)(p6 & 32767u), h6, a6);
            a7 = fmaf((float)(p7 & 32767u), h7, a7);
        }
        for (; i + 3 < e; i += 4) {
            unsigned int p0 = epack[i], p1 = epack[i + 1], p2 = epack[i + 2], p3 = epack[i + 3];
            a0 = fmaf((float)(p0 & 32767u), bf2f(hl[(size_t)(p0 >> 15) * D]), a0);
            a1 = fmaf((float)(p1 & 32767u), bf2f(hl[(size_t)(p1 >> 15) * D]), a1);
            a2 = fmaf((float)(p2 & 32767u), bf2f(hl[(size_t)(p2 >> 15) * D]), a2);
            a3 = fmaf((float)(p3 & 32767u), bf2f(hl[(size_t)(p3 >> 15) * D]), a3);
        }
        for (; i < e; ++i) {
            unsigned int p = epack[i];
            a0 = fmaf((float)(p & 32767u), bf2f(hl[(size_t)(p >> 15) * D]), a0);
        }
        float acc = (((a0 + a1) + (a2 + a3)) + ((a4 + a5) + (a6 + a7))) * ndq[n];
        if (FINAL) out[(size_t)n * D + lane] = acc + bias[lane];
        else       out[(size_t)n * D + lane] = acc;
    }
}

extern "C" void kernel_launch(void* const* d_in, const int* in_sizes, int n_in,
                              void* d_out, int out_size, void* d_ws, size_t ws_size,
                              hipStream_t stream) {
    const float* features = (const float*)d_in[0];
    const float* ew       = (const float*)d_in[1];
    const int*   src      = (const int*)d_in[2];
    const int*   dst      = (const int*)d_in[3];
    const float* W1       = (const float*)d_in[4];
    const float* b1       = (const float*)d_in[5];
    const float* W2       = (const float*)d_in[6];
    const float* b2       = (const float*)d_in[7];
    const float* Wp       = (const float*)d_in[8];
    const float* bp       = (const float*)d_in[9];
    float* out = (float*)d_out;

    // workspace layout (explicit 4B-unit offsets)
    float* ws = (float*)d_ws;
    float* norm_src = ws;                             // @0        N
    float* ndq      = ws + 100000;                    // @100000   N  (nd / 32767)
    int*   deg_int  = (int*)(ws + 200000);            // @200000   N
    int*   row_ptr  = (int*)(ws + 300000);            // @300000   N+1
    int*   block_sums = (int*)(ws + 400002);          // @400002   NB_SCAN
    int*   block_off  = (int*)(ws + 400394);          // @400394   NB_SCAN
    unsigned short* rank16 = (unsigned short*)(ws + 400800);  // 1.6M u16
    unsigned int*   epack  = (unsigned int*)(ws + 1200800);   // E u32
    unsigned short* hbuf   = (unsigned short*)(ws + 2800800); // N*64 bf16 (3.2M f)
    float*          bufA   = ws + 6000800;                    // N*64 fp32 (6.4M f)

    // slice-count buffers alias hbuf/bufA (dead once fill completes)
    unsigned short* slicecnt_dst = hbuf;                    // becomes sliceoff
    unsigned short* slicecnt_src = (unsigned short*)bufA;

    // ---- CSR + norms build: zero global atomics ----
    count_kernel<true><<<NSLICE * NBUCK, 512, 0, stream>>>(dst, slicecnt_dst, rank16);
    count_kernel<false><<<NSLICE * NBUCK, 512, 0, stream>>>(src, slicecnt_src, nullptr);
    scan_slices_kernel<<<NB_SCAN, 256, 0, stream>>>(slicecnt_dst, slicecnt_src,
                                                    deg_int, ndq, norm_src);
    block_sum_kernel<<<NB_SCAN, 256, 0, stream>>>(deg_int, block_sums);
    scan_blocks_kernel<<<1, 512, 0, stream>>>(block_sums, block_off);
    scatter_rowptr_kernel<<<NB_SCAN, 256, 0, stream>>>(deg_int, block_off, row_ptr);
    fill_kernel<<<2048, 256, 0, stream>>>(src, dst, ew, row_ptr,
                                          slicecnt_dst, rank16, epack);

    // ---- layer 1: h1 = ns ⊙ (features @ W1) ; bufA = ndq ⊙ Σ ew·h1
    matmul_kernel<64, 64, false><<<1563, 256, 0, stream>>>(features, W1, nullptr, norm_src, hbuf);
    csr_agg_kernel<64, false><<<4096, 256, 0, stream>>>(row_ptr, epack, hbuf, ndq, nullptr, bufA);

    // ---- layer 2: h2 = ns ⊙ (relu(bufA + b1) @ W2) ; bufA = ndq ⊙ Σ ew·h2
    matmul_kernel<64, 64, true><<<1563, 256, 0, stream>>>(bufA, W2, b1, norm_src, hbuf);
    csr_agg_kernel<64, false><<<4096, 256, 0, stream>>>(row_ptr, epack, hbuf, ndq, nullptr, bufA);

    // ---- layer 3: h3 = ns ⊙ (relu(bufA + b2) @ Wp) ; out = ndq ⊙ Σ ew·h3 + bp
    matmul_kernel<128, 32, true><<<782, 256, 0, stream>>>(bufA, Wp, b2, norm_src, hbuf);
    csr_agg_kernel<32, true><<<4096, 256, 0, stream>>>(row_ptr, epack, hbuf, ndq, bp, out);
}